// Round 9
// baseline (1333.101 us; speedup 1.0000x reference)
//
#include <hip/hip_runtime.h>
#include <hip/hip_cooperative_groups.h>
#include <math.h>

namespace cg = cooperative_groups;

// Problem constants
#define TT 80
#define BS 8
#define NA 6
#define DMODEL 768
#define NH 4
#define DH 192
#define FFD 1024
#define NROWS (TT*BS)   // 640
#define NQKV (3*DMODEL) // 2304

typedef __bf16 bf16;
typedef __bf16 bf16x8 __attribute__((ext_vector_type(8)));
typedef float  f32x4  __attribute__((ext_vector_type(4)));

struct MegaParams {
    const float *x; const int *y; const int *ind_map; const int *act_ts;
    const float *skel_W, *skel_b, *muQ, *sigQ;
    const float *Wq, *bq, *Wk, *bk, *Wv, *bv, *Wo, *bo, *W1, *b1, *W2, *b2;
    const float *ln1_g, *ln1_b, *ln2_g, *ln2_b, *lnf_g, *lnf_b;
    float *out;
    float *hF, *h1F, *tmp;
    bf16 *qkvB, *hB, *h1B, *attB, *ffn1B, *qkvT, *woT, *w1T, *w2T;
};

// ---------------- stage: all-layer weight transpose + bf16 cast ----------------
__device__ void transpose_stage(const MegaParams& p, char* smem) {
    float (*tile)[33] = (float(*)[33])smem;
    int tx = threadIdx.x & 31, ty = threadIdx.x >> 5;  // 32 x 8
    for (int idx = blockIdx.x; idx < 4 * 3840; idx += gridDim.x) {
        int l = idx / 3840, r = idx % 3840;
        int z, kt, nt, K, ldsrc;
        if (r < 1728)      { z = 0; K = 768;  ldsrc = 768;  kt = r / 72;  nt = r % 72; }
        else if (r < 2304) { z = 1; K = 768;  ldsrc = 768;  r -= 1728; kt = r / 24; nt = r % 24; }
        else if (r < 3072) { z = 2; K = 768;  ldsrc = 1024; r -= 2304; kt = r / 32; nt = r % 32; }
        else               { z = 3; K = 1024; ldsrc = 768;  r -= 3072; kt = r / 24; nt = r % 24; }
        int k0 = kt * 32, n0 = nt * 32;
        const float* src; bf16* dst; int ncol;
        if (z == 0) {
            // 768 is NOT a power of two — subtract segment base (R2 bug).
            if (n0 < 768)       { src = p.Wq + (size_t)l * 768 * 768; ncol = n0; }
            else if (n0 < 1536) { src = p.Wk + (size_t)l * 768 * 768; ncol = n0 - 768; }
            else                { src = p.Wv + (size_t)l * 768 * 768; ncol = n0 - 1536; }
            dst = p.qkvT + (size_t)l * NQKV * DMODEL;
        } else if (z == 1) { src = p.Wo + (size_t)l * 768 * 768;  dst = p.woT + (size_t)l * 768 * 768;  ncol = n0; }
        else if (z == 2)   { src = p.W1 + (size_t)l * 768 * 1024; dst = p.w1T + (size_t)l * 1024 * 768; ncol = n0; }
        else               { src = p.W2 + (size_t)l * 1024 * 768; dst = p.w2T + (size_t)l * 768 * 1024; ncol = n0; }
        __syncthreads();   // protect tile reuse
#pragma unroll
        for (int i = 0; i < 4; i++) {
            int rr = ty + 8 * i;
            tile[rr][tx] = src[(size_t)(k0 + rr) * ldsrc + ncol + tx];
        }
        __syncthreads();
#pragma unroll
        for (int i = 0; i < 4; i++) {
            int rr = ty + 8 * i;
            dst[(size_t)(n0 + rr) * K + k0 + tx] = (bf16)tile[tx][rr];
        }
    }
}

// ---------------- stage: embedding + positional encoding ----------------
__device__ void embed_stage(const MegaParams& p, char* smem) {
    float* xrow = (float*)smem;
    int c = threadIdx.x;
    for (int r = blockIdx.x; r < NROWS; r += gridDim.x) {
        int t = r >> 3, b = r & 7;
        __syncthreads();
        if (c < 150) xrow[c] = p.x[(b * 150 + c) * TT + t];
        __syncthreads();
        float acc = p.skel_b[c];
        for (int jf = 0; jf < 150; jf++) acc += xrow[jf] * p.skel_W[jf * 256 + c];
        int ind_t = p.ind_map[t * 8 + b];
        int yb = p.y[b * NA + ind_t];
        float cm = p.muQ[yb * 256 + c];
        float cs = p.sigQ[yb * 256 + c];
        int start = (t == 0) ? 0 : (t + 2);
        float div = expf((float)(c & ~1) * (-9.210340371976184f / 256.0f));
        float p0, p1, p2;
        if (c & 1) {
            p0 = cosf((float)start * div);
            p1 = cosf((float)(start + 1) * div);
            p2 = cosf((float)(start + 2) * div);
        } else {
            p0 = sinf((float)start * div);
            p1 = sinf((float)(start + 1) * div);
            p2 = sinf((float)(start + 2) * div);
        }
        float v0 = cm + p0, v1 = cs + p1, v2 = acc + p2;
        float* hr = p.hF + (size_t)r * DMODEL;
        hr[c] = v0; hr[c + 256] = v1; hr[c + 512] = v2;
        bf16* hb = p.hB + (size_t)r * DMODEL;
        hb[c] = (bf16)v0; hb[c + 256] = (bf16)v1; hb[c + 512] = (bf16)v2;
    }
}

// ---------------- stage: bf16 MFMA GEMM, tile 64x64, LDS double-buffered -------
// EPI: 0 = QKV (bias by col segment, elu+1 on cols<1536, bf16 out)
//      1 = bias + f32 resid, f32 out
//      2 = bias + relu, bf16 out
template <int EPI>
__device__ void gemm_stage(const bf16* __restrict__ A, const bf16* __restrict__ Bt,
        const float* __restrict__ bias_q, const float* __restrict__ bias_k,
        const float* __restrict__ bias_v, const float* __restrict__ resid,
        float* __restrict__ outF, bf16* __restrict__ outB,
        int M, int N, int K, char* smem) {
    bf16 (*As0)[40] = (bf16(*)[40])smem;
    bf16 (*As1)[40] = (bf16(*)[40])(smem + 5120);
    bf16 (*Bs0)[40] = (bf16(*)[40])(smem + 10240);
    bf16 (*Bs1)[40] = (bf16(*)[40])(smem + 15360);
    int tid = threadIdx.x;
    int w = tid >> 6, l = tid & 63;
    int lm = l & 15, lq = l >> 4;
    int sr = tid >> 2, sk = (tid & 3) * 8;
    int ntn = N >> 6;
    int ntiles = (M >> 6) * ntn;
    for (int tile = blockIdx.x; tile < ntiles; tile += gridDim.x) {
        int m0 = (tile / ntn) << 6, n0 = (tile % ntn) << 6;
        const bf16* Arow = &A[(size_t)(m0 + sr) * K];
        const bf16* Brow = &Bt[(size_t)(n0 + sr) * K];
        f32x4 acc[4] = {};
        uint4 a0 = *(const uint4*)&Arow[sk];
        uint4 a1 = *(const uint4*)&Arow[32 + sk];
        uint4 b0 = *(const uint4*)&Brow[sk];
        uint4 b1 = *(const uint4*)&Brow[32 + sk];
        for (int k0 = 0; k0 < K; k0 += 64) {
            __syncthreads();
            *(uint4*)&As0[sr][sk] = a0;
            *(uint4*)&As1[sr][sk] = a1;
            *(uint4*)&Bs0[sr][sk] = b0;
            *(uint4*)&Bs1[sr][sk] = b1;
            __syncthreads();
            int k2 = k0 + 64; if (k2 >= K) k2 = 0;   // tail: harmless re-read
            a0 = *(const uint4*)&Arow[k2 + sk];
            a1 = *(const uint4*)&Arow[k2 + 32 + sk];
            b0 = *(const uint4*)&Brow[k2 + sk];
            b1 = *(const uint4*)&Brow[k2 + 32 + sk];
            bf16x8 af0 = *(bf16x8*)&As0[w * 16 + lm][lq * 8];
            bf16x8 af1 = *(bf16x8*)&As1[w * 16 + lm][lq * 8];
#pragma unroll
            for (int nb = 0; nb < 4; nb++) {
                bf16x8 bf0 = *(bf16x8*)&Bs0[nb * 16 + lm][lq * 8];
                acc[nb] = __builtin_amdgcn_mfma_f32_16x16x32_bf16(af0, bf0, acc[nb], 0, 0, 0);
            }
#pragma unroll
            for (int nb = 0; nb < 4; nb++) {
                bf16x8 bf1 = *(bf16x8*)&Bs1[nb * 16 + lm][lq * 8];
                acc[nb] = __builtin_amdgcn_mfma_f32_16x16x32_bf16(af1, bf1, acc[nb], 0, 0, 0);
            }
        }
        // C layout: row = m0 + w*16 + lq*4 + r, col = n0 + nb*16 + lm
#pragma unroll
        for (int nb = 0; nb < 4; nb++) {
            int col = n0 + nb * 16 + lm;
            float b;
            bool do_elu = false;
            if (EPI == 0) {
                if (col < 768)       { b = bias_q[col];        do_elu = true; }
                else if (col < 1536) { b = bias_k[col - 768];  do_elu = true; }
                else                 { b = bias_v[col - 1536]; }
            } else {
                b = bias_q[col];
            }
#pragma unroll
            for (int r = 0; r < 4; r++) {
                int row = m0 + w * 16 + lq * 4 + r;
                float v = acc[nb][r] + b;
                if (EPI == 0) {
                    if (do_elu) v = (v > 0.0f) ? (v + 1.0f) : expf(v);
                    outB[(size_t)row * N + col] = (bf16)v;
                } else if (EPI == 1) {
                    v += resid[(size_t)row * N + col];
                    outF[(size_t)row * N + col] = v;
                } else {
                    v = fmaxf(v, 0.0f);
                    outB[(size_t)row * N + col] = (bf16)v;
                }
            }
        }
    }
}

// ---------------- stage: row LayerNorm over 768, one wave per row -------------
__device__ void ln_stage(const float* __restrict__ in, float* __restrict__ outF,
        bf16* __restrict__ outB, const float* __restrict__ g,
        const float* __restrict__ b) {
    int wave = threadIdx.x >> 6, lane = threadIdx.x & 63;
    for (int row = blockIdx.x * 4 + wave; row < NROWS; row += gridDim.x * 4) {
        const float* xr = in + (size_t)row * DMODEL;
        float4 v[3];
        float s = 0.0f;
#pragma unroll
        for (int j = 0; j < 3; j++) {
            v[j] = *(const float4*)&xr[lane * 4 + 256 * j];
            s += v[j].x + v[j].y + v[j].z + v[j].w;
        }
#pragma unroll
        for (int mk = 1; mk < 64; mk <<= 1) s += __shfl_xor(s, mk, 64);
        float m = s * (1.0f / 768.0f);
        float sq = 0.0f;
#pragma unroll
        for (int j = 0; j < 3; j++) {
            v[j].x -= m; v[j].y -= m; v[j].z -= m; v[j].w -= m;
            sq += v[j].x * v[j].x + v[j].y * v[j].y + v[j].z * v[j].z + v[j].w * v[j].w;
        }
#pragma unroll
        for (int mk = 1; mk < 64; mk <<= 1) sq += __shfl_xor(sq, mk, 64);
        float r = rsqrtf(sq * (1.0f / 768.0f) + 1e-5f);
        float* orow = outF + (size_t)row * DMODEL;
        bf16* brow = outB + (size_t)row * DMODEL;
#pragma unroll
        for (int j = 0; j < 3; j++) {
            int c = lane * 4 + 256 * j;
            float4 gg = *(const float4*)&g[c];
            float4 bb = *(const float4*)&b[c];
            float o0 = v[j].x * r * gg.x + bb.x;
            float o1 = v[j].y * r * gg.y + bb.y;
            float o2 = v[j].z * r * gg.z + bb.z;
            float o3 = v[j].w * r * gg.w + bb.w;
            *(float4*)&orow[c] = make_float4(o0, o1, o2, o3);
            bf16 t4[4] = {(bf16)o0, (bf16)o1, (bf16)o2, (bf16)o3};
            *(uint2*)&brow[c] = *(uint2*)t4;
        }
    }
}

// ---------------- stage: causal linear attention (two MFMA matmuls) -----------
// 32 active blocks (b,h), 256 threads; wave w owns row-tiles {w} (+{4} for w=0).
__device__ void attn_stage(const bf16* __restrict__ qkvB, bf16* __restrict__ att,
                           char* smem) {
    if (blockIdx.x >= 32) return;
    bf16* Qs  = (bf16*)smem;            // [80][200]
    bf16* Ks  = (bf16*)(smem + 32000);  // [80][200]
    bf16* Aij = (bf16*)smem;            // [80][104]  (overlays Qs after phase 1)
    bf16* VT  = (bf16*)(smem + 16640);  // [192][104] (overlays rest)
    int b = blockIdx.x >> 2, h = blockIdx.x & 3;
    int tid = threadIdx.x;
    int w = tid >> 6, l = tid & 63;
    int lm = l & 15, lq = l >> 4;

    for (int c = tid; c < 1920; c += 256) {
        int t = c / 24, d0 = (c % 24) * 8;
        size_t g = (size_t)(t * 8 + b) * NQKV + h * DH + d0;
        *(uint4*)&Qs[t * 200 + d0] = *(const uint4*)&qkvB[g];
        *(uint4*)&Ks[t * 200 + d0] = *(const uint4*)&qkvB[g + 768];
    }
    __syncthreads();

    float mval[2][5][4];
    float inv[2][4];
    int nrt = (w == 0) ? 2 : 1;
    for (int i = 0; i < nrt; i++) {
        int rt = w + i * 4;
        f32x4 acc[5] = {};
#pragma unroll
        for (int k0 = 0; k0 < 192; k0 += 32) {
            bf16x8 af = *(bf16x8*)&Qs[(rt * 16 + lm) * 200 + lq * 8 + k0];
#pragma unroll
            for (int nb = 0; nb < 5; nb++) {
                bf16x8 bfr = *(bf16x8*)&Ks[(nb * 16 + lm) * 200 + lq * 8 + k0];
                acc[nb] = __builtin_amdgcn_mfma_f32_16x16x32_bf16(af, bfr, acc[nb], 0, 0, 0);
            }
        }
        float rs[4] = {0.f, 0.f, 0.f, 0.f};
#pragma unroll
        for (int nb = 0; nb < 5; nb++)
#pragma unroll
            for (int r = 0; r < 4; r++) {
                int t = rt * 16 + lq * 4 + r, tau = nb * 16 + lm;
                float v = (tau <= t) ? acc[nb][r] : 0.0f;
                mval[i][nb][r] = v;
                rs[r] += v;
            }
#pragma unroll
        for (int mk = 1; mk < 16; mk <<= 1)
#pragma unroll
            for (int r = 0; r < 4; r++) rs[r] += __shfl_xor(rs[r], mk, 64);
#pragma unroll
        for (int r = 0; r < 4; r++) inv[i][r] = 1.0f / (rs[r] + 1e-6f);
    }
    __syncthreads();   // all phase-1 Qs/Ks reads done before overlay

    for (int i = 0; i < nrt; i++) {
        int rt = w + i * 4;
#pragma unroll
        for (int nb = 0; nb < 5; nb++)
#pragma unroll
            for (int r = 0; r < 4; r++)
                Aij[(rt * 16 + lq * 4 + r) * 104 + nb * 16 + lm] = (bf16)mval[i][nb][r];
    }
    for (int c2 = tid; c2 < 320; c2 += 256)
        *(uint2*)&Aij[(c2 >> 2) * 104 + 80 + (c2 & 3) * 4] = make_uint2(0u, 0u);
    for (int c = tid; c < 1920; c += 256) {
        int t = c / 24, d0 = (c % 24) * 8;
        uint4 vv = *(const uint4*)&qkvB[(size_t)(t * 8 + b) * NQKV + h * DH + 1536 + d0];
        bf16 t8[8];
        *(uint4*)t8 = vv;
#pragma unroll
        for (int j = 0; j < 8; j++) VT[(d0 + j) * 104 + t] = t8[j];
    }
    if (tid < 192) {
        *(uint4*)&VT[tid * 104 + 80] = make_uint4(0u, 0u, 0u, 0u);
        *(uint4*)&VT[tid * 104 + 88] = make_uint4(0u, 0u, 0u, 0u);
    }
    __syncthreads();

    for (int i = 0; i < nrt; i++) {
        int rt = w + i * 4;
#pragma unroll 1
        for (int nc = 0; nc < 12; nc++) {
            f32x4 a2 = {};
#pragma unroll
            for (int k0 = 0; k0 < 96; k0 += 32) {
                bf16x8 af  = *(bf16x8*)&Aij[(rt * 16 + lm) * 104 + lq * 8 + k0];
                bf16x8 bfr = *(bf16x8*)&VT[(nc * 16 + lm) * 104 + lq * 8 + k0];
                a2 = __builtin_amdgcn_mfma_f32_16x16x32_bf16(af, bfr, a2, 0, 0, 0);
            }
#pragma unroll
            for (int r = 0; r < 4; r++) {
                int t = rt * 16 + lq * 4 + r;
                att[(size_t)(t * 8 + b) * DMODEL + h * DH + nc * 16 + lm] =
                    (bf16)(a2[r] * inv[i][r]);
            }
        }
    }
}

// ---------------- stage: final LN + output gather ----------------
__device__ void final_stage(const MegaParams& p, char* smem) {
    if (blockIdx.x >= 48) return;
    float* sm4 = (float*)smem;
    int ba = blockIdx.x;
    int b = ba / NA;
    int ts = p.act_ts[ba];
    int t = ts - 1; if (t < 0) t = 0;
    const float* xr = p.hF + (size_t)(t * 8 + b) * DMODEL;
    int c = threadIdx.x;
    int lane = c & 63, wid = c >> 6;
    float x0 = xr[c], x1 = xr[c + 256], x2 = xr[c + 512];
    float s = x0 + x1 + x2;
#pragma unroll
    for (int off = 32; off > 0; off >>= 1) s += __shfl_down(s, off, 64);
    if (lane == 0) sm4[wid] = s;
    __syncthreads();
    float m = (sm4[0] + sm4[1] + sm4[2] + sm4[3]) * (1.0f / 768.0f);
    __syncthreads();
    float d0 = x0 - m, d1 = x1 - m, d2 = x2 - m;
    float q = d0 * d0 + d1 * d1 + d2 * d2;
#pragma unroll
    for (int off = 32; off > 0; off >>= 1) q += __shfl_down(q, off, 64);
    if (lane == 0) sm4[wid] = q;
    __syncthreads();
    float v = (sm4[0] + sm4[1] + sm4[2] + sm4[3]) * (1.0f / 768.0f);
    float r = rsqrtf(v + 1e-5f);
    p.out[ba * 256 + c]            = d0 * r * p.lnf_g[c] + p.lnf_b[c];             // mu
    p.out[48 * 256 + ba * 256 + c] = d1 * r * p.lnf_g[c + 256] + p.lnf_b[c + 256]; // logvar
}

// ---------------- the mega-kernel (cooperative, 256 blocks = 1/CU) ------------
__global__ __launch_bounds__(256) void mega(MegaParams p) {
    __shared__ __attribute__((aligned(16))) char smem[64000];
    cg::grid_group grid = cg::this_grid();

    transpose_stage(p, smem);
    embed_stage(p, smem);
    grid.sync();

    for (int l = 0; l < 4; l++) {
        const bf16* qkvTl = p.qkvT + (size_t)l * NQKV * DMODEL;
        const bf16* woTl  = p.woT  + (size_t)l * DMODEL * DMODEL;
        const bf16* w1Tl  = p.w1T  + (size_t)l * FFD * DMODEL;
        const bf16* w2Tl  = p.w2T  + (size_t)l * DMODEL * FFD;
        gemm_stage<0>(p.hB, qkvTl, p.bq + l * DMODEL, p.bk + l * DMODEL,
                      p.bv + l * DMODEL, nullptr, nullptr, p.qkvB,
                      NROWS, NQKV, DMODEL, smem);
        grid.sync();
        attn_stage(p.qkvB, p.attB, smem);
        grid.sync();
        gemm_stage<1>(p.attB, woTl, p.bo + l * DMODEL, nullptr, nullptr,
                      p.hF, p.tmp, nullptr, NROWS, DMODEL, DMODEL, smem);
        grid.sync();
        ln_stage(p.tmp, p.h1F, p.h1B, p.ln1_g + l * DMODEL, p.ln1_b + l * DMODEL);
        grid.sync();
        gemm_stage<2>(p.h1B, w1Tl, p.b1 + l * FFD, nullptr, nullptr,
                      nullptr, nullptr, p.ffn1B, NROWS, FFD, DMODEL, smem);
        grid.sync();
        gemm_stage<1>(p.ffn1B, w2Tl, p.b2 + l * DMODEL, nullptr, nullptr,
                      p.h1F, p.tmp, nullptr, NROWS, DMODEL, FFD, smem);
        grid.sync();
        ln_stage(p.tmp, p.hF, p.hB, p.ln2_g + l * DMODEL, p.ln2_b + l * DMODEL);
        grid.sync();
    }

    final_stage(p, smem);
}

// ---------------- fallback wrappers (R5-style multi-dispatch) ----------------
__global__ __launch_bounds__(256) void transpose_wrap(MegaParams p) {
    __shared__ __attribute__((aligned(16))) char smem[4352];
    transpose_stage(p, smem);
}
__global__ __launch_bounds__(256) void embed_wrap(MegaParams p) {
    __shared__ __attribute__((aligned(16))) char smem[640];
    embed_stage(p, smem);
}
template <int EPI>
__global__ __launch_bounds__(256) void gemm_wrap(
        const bf16* A, const bf16* Bt, const float* bq, const float* bk,
        const float* bv, const float* resid, float* outF, bf16* outB,
        int M, int N, int K) {
    __shared__ __attribute__((aligned(16))) char smem[20480];
    gemm_stage<EPI>(A, Bt, bq, bk, bv, resid, outF, outB, M, N, K, smem);
}
__global__ __launch_bounds__(256) void attn_wrap(const bf16* qkvB, bf16* att) {
    __shared__ __attribute__((aligned(16))) char smem[64000];
    attn_stage(qkvB, att, smem);
}
__global__ __launch_bounds__(256) void ln_wrap(const float* in, float* outF,
        bf16* outB, const float* g, const float* b) {
    ln_stage(in, outF, outB, g, b);
}
__global__ __launch_bounds__(256) void final_wrap(MegaParams p) {
    __shared__ __attribute__((aligned(16))) char smem[64];
    final_stage(p, smem);
}

extern "C" void kernel_launch(void* const* d_in, const int* in_sizes, int n_in,
                              void* d_out, int out_size, void* d_ws, size_t ws_size,
                              hipStream_t stream) {
    MegaParams prm;
    prm.x       = (const float*)d_in[0];
    prm.y       = (const int*)d_in[1];
    prm.ind_map = (const int*)d_in[2];
    prm.act_ts  = (const int*)d_in[3];
    prm.skel_W  = (const float*)d_in[4];
    prm.skel_b  = (const float*)d_in[5];
    prm.muQ     = (const float*)d_in[6];
    prm.sigQ    = (const float*)d_in[7];
    prm.Wq = (const float*)d_in[8];   prm.bq = (const float*)d_in[9];
    prm.Wk = (const float*)d_in[10];  prm.bk = (const float*)d_in[11];
    prm.Wv = (const float*)d_in[12];  prm.bv = (const float*)d_in[13];
    prm.Wo = (const float*)d_in[14];  prm.bo = (const float*)d_in[15];
    prm.W1 = (const float*)d_in[16];  prm.b1 = (const float*)d_in[17];
    prm.W2 = (const float*)d_in[18];  prm.b2 = (const float*)d_in[19];
    prm.ln1_g = (const float*)d_in[20]; prm.ln1_b = (const float*)d_in[21];
    prm.ln2_g = (const float*)d_in[22]; prm.ln2_b = (const float*)d_in[23];
    prm.lnf_g = (const float*)d_in[24]; prm.lnf_b = (const float*)d_in[25];
    prm.out = (float*)d_out;

    // ---- workspace layout (all 16B aligned) ----
    char* p = (char*)d_ws;
    const size_t R = (size_t)NROWS * DMODEL;       // 491520
    prm.hF    = (float*)p; p += R * 4;
    prm.h1F   = (float*)p; p += R * 4;
    prm.tmp   = (float*)p; p += R * 4;
    prm.qkvB  = (bf16*)p;  p += (size_t)NROWS * NQKV * 2;
    prm.hB    = (bf16*)p;  p += R * 2;
    prm.h1B   = (bf16*)p;  p += R * 2;
    prm.attB  = (bf16*)p;  p += R * 2;
    prm.ffn1B = (bf16*)p;  p += (size_t)NROWS * FFD * 2;
    prm.qkvT  = (bf16*)p;  p += (size_t)4 * NQKV * DMODEL * 2;
    prm.woT   = (bf16*)p;  p += (size_t)4 * DMODEL * DMODEL * 2;
    prm.w1T   = (bf16*)p;  p += (size_t)4 * FFD * DMODEL * 2;
    prm.w2T   = (bf16*)p;  p += (size_t)4 * DMODEL * FFD * 2;

    void* kargs[] = { (void*)&prm };
    hipError_t err = hipLaunchCooperativeKernel((const void*)mega, dim3(256),
                                                dim3(256), kargs, 0, stream);
    if (err != hipSuccess) {
        // Fallback: proven R5-style multi-dispatch sequence (same stages).
        transpose_wrap<<<512, 256, 0, stream>>>(prm);
        embed_wrap<<<NROWS, 256, 0, stream>>>(prm);
        for (int l = 0; l < 4; l++) {
            const bf16* qkvTl = prm.qkvT + (size_t)l * NQKV * DMODEL;
            const bf16* woTl  = prm.woT  + (size_t)l * DMODEL * DMODEL;
            const bf16* w1Tl  = prm.w1T  + (size_t)l * FFD * DMODEL;
            const bf16* w2Tl  = prm.w2T  + (size_t)l * DMODEL * FFD;
            gemm_wrap<0><<<360, 256, 0, stream>>>(prm.hB, qkvTl,
                    prm.bq + l * DMODEL, prm.bk + l * DMODEL, prm.bv + l * DMODEL,
                    nullptr, nullptr, prm.qkvB, NROWS, NQKV, DMODEL);
            attn_wrap<<<32, 256, 0, stream>>>(prm.qkvB, prm.attB);
            gemm_wrap<1><<<120, 256, 0, stream>>>(prm.attB, woTl,
                    prm.bo + l * DMODEL, nullptr, nullptr, prm.hF,
                    prm.tmp, nullptr, NROWS, DMODEL, DMODEL);
            ln_wrap<<<160, 256, 0, stream>>>(prm.tmp, prm.h1F, prm.h1B,
                    prm.ln1_g + l * DMODEL, prm.ln1_b + l * DMODEL);
            gemm_wrap<2><<<160, 256, 0, stream>>>(prm.h1B, w1Tl,
                    prm.b1 + l * FFD, nullptr, nullptr, nullptr,
                    nullptr, prm.ffn1B, NROWS, FFD, DMODEL);
            gemm_wrap<1><<<120, 256, 0, stream>>>(prm.ffn1B, w2Tl,
                    prm.b2 + l * DMODEL, nullptr, nullptr, prm.h1F,
                    prm.tmp, nullptr, NROWS, DMODEL, FFD);
            ln_wrap<<<160, 256, 0, stream>>>(prm.tmp, prm.hF, prm.hB,
                    prm.ln2_g + l * DMODEL, prm.ln2_b + l * DMODEL);
        }
        final_wrap<<<48, 256, 0, stream>>>(prm);
    }
}

// Round 10
// 426.340 us; speedup vs baseline: 3.1269x; 3.1269x over previous
//
#include <hip/hip_runtime.h>
#include <math.h>

// Problem constants
#define TT 80
#define BS 8
#define NA 6
#define DMODEL 768
#define NH 4
#define DH 192
#define FFD 1024
#define NROWS (TT*BS)   // 640
#define NQKV (3*DMODEL) // 2304

typedef __bf16 bf16;
typedef __bf16 bf16x8 __attribute__((ext_vector_type(8)));
typedef float  f32x4  __attribute__((ext_vector_type(4)));

// ---------------- block reduce (256 threads, 4 waves of 64) ----------------
__device__ __forceinline__ float block_reduce_sum256(float v, float* sm4) {
#pragma unroll
    for (int off = 32; off > 0; off >>= 1) v += __shfl_down(v, off, 64);
    int lane = threadIdx.x & 63, wid = threadIdx.x >> 6;
    if (lane == 0) sm4[wid] = v;
    __syncthreads();
    float r = sm4[0] + sm4[1] + sm4[2] + sm4[3];
    __syncthreads();
    return r;
}

// ---------------- prep: weight transpose (blocks 0..511) + embed (512..1151) --
// The two halves are fully independent -> one dispatch, saves a launch gap.
__global__ __launch_bounds__(256) void prep_k(
        const float* __restrict__ x, const int* __restrict__ y,
        const int* __restrict__ ind_map, const float* __restrict__ skel_W,
        const float* __restrict__ skel_b, const float* __restrict__ muQ,
        const float* __restrict__ sigQ, float* __restrict__ h0,
        bf16* __restrict__ h0b,
        const float* __restrict__ Wq, const float* __restrict__ Wk,
        const float* __restrict__ Wv, const float* __restrict__ Wo,
        const float* __restrict__ W1, const float* __restrict__ W2,
        bf16* __restrict__ qkvT, bf16* __restrict__ woT,
        bf16* __restrict__ w1T, bf16* __restrict__ w2T) {
    __shared__ __attribute__((aligned(16))) char smem[4352];
    if (blockIdx.x < 512) {
        // ---- weight transpose: 15360 32x32 tiles, grid-stride over 512 blocks
        float (*tile)[33] = (float(*)[33])smem;
        int tx = threadIdx.x & 31, ty = threadIdx.x >> 5;  // 32 x 8
        for (int idx = blockIdx.x; idx < 4 * 3840; idx += 512) {
            int l = idx / 3840, r = idx % 3840;
            int z, kt, nt, K, ldsrc;
            if (r < 1728)      { z = 0; K = 768;  ldsrc = 768;  kt = r / 72;  nt = r % 72; }
            else if (r < 2304) { z = 1; K = 768;  ldsrc = 768;  r -= 1728; kt = r / 24; nt = r % 24; }
            else if (r < 3072) { z = 2; K = 768;  ldsrc = 1024; r -= 2304; kt = r / 32; nt = r % 32; }
            else               { z = 3; K = 1024; ldsrc = 768;  r -= 3072; kt = r / 24; nt = r % 24; }
            int k0 = kt * 32, n0 = nt * 32;
            const float* src; bf16* dst; int ncol;
            if (z == 0) {
                // 768 is NOT a power of two — subtract segment base (R2 bug).
                if (n0 < 768)       { src = Wq + (size_t)l * 768 * 768; ncol = n0; }
                else if (n0 < 1536) { src = Wk + (size_t)l * 768 * 768; ncol = n0 - 768; }
                else                { src = Wv + (size_t)l * 768 * 768; ncol = n0 - 1536; }
                dst = qkvT + (size_t)l * NQKV * DMODEL;
            } else if (z == 1) { src = Wo + (size_t)l * 768 * 768;  dst = woT + (size_t)l * 768 * 768;  ncol = n0; }
            else if (z == 2)   { src = W1 + (size_t)l * 768 * 1024; dst = w1T + (size_t)l * 1024 * 768; ncol = n0; }
            else               { src = W2 + (size_t)l * 1024 * 768; dst = w2T + (size_t)l * 768 * 1024; ncol = n0; }
            __syncthreads();   // protect tile reuse across grid-stride iters
#pragma unroll
            for (int i = 0; i < 4; i++) {
                int rr = ty + 8 * i;
                tile[rr][tx] = src[(size_t)(k0 + rr) * ldsrc + ncol + tx];
            }
            __syncthreads();
#pragma unroll
            for (int i = 0; i < 4; i++) {
                int rr = ty + 8 * i;
                dst[(size_t)(n0 + rr) * K + k0 + tx] = (bf16)tile[tx][rr];
            }
        }
    } else {
        // ---- embedding + positional encoding, one block per row
        float* xrow = (float*)smem;
        int r = blockIdx.x - 512;
        int t = r >> 3, b = r & 7;
        int c = threadIdx.x;
        if (c < 150) xrow[c] = x[(b * 150 + c) * TT + t];
        __syncthreads();
        float acc = skel_b[c];
        for (int jf = 0; jf < 150; jf++) acc += xrow[jf] * skel_W[jf * 256 + c];
        int ind_t = ind_map[t * 8 + b];
        int yb = y[b * NA + ind_t];
        float cm = muQ[yb * 256 + c];
        float cs = sigQ[yb * 256 + c];
        int start = (t == 0) ? 0 : (t + 2);
        float div = expf((float)(c & ~1) * (-9.210340371976184f / 256.0f));
        float p0, p1, p2;
        if (c & 1) {
            p0 = cosf((float)start * div);
            p1 = cosf((float)(start + 1) * div);
            p2 = cosf((float)(start + 2) * div);
        } else {
            p0 = sinf((float)start * div);
            p1 = sinf((float)(start + 1) * div);
            p2 = sinf((float)(start + 2) * div);
        }
        float* hr = h0 + (size_t)r * DMODEL;
        float v0 = cm + p0, v1 = cs + p1, v2 = acc + p2;
        hr[c] = v0; hr[c + 256] = v1; hr[c + 512] = v2;
        bf16* hb = h0b + (size_t)r * DMODEL;
        hb[c] = (bf16)v0; hb[c + 256] = (bf16)v1; hb[c + 512] = (bf16)v2;
    }
}

// ---------------- bf16 MFMA GEMM: tile 64x64, 256 threads (R5 champion) ------
// K-loop pipelined: unroll 64, register prefetch of next chunk issued right
// after the LDS-write barrier so global (L2) latency overlaps MFMA+ds_read.
// A [M,K] row-major bf16; Bt [N,K] row-major bf16.  K % 64 == 0.
// EPI: 0 = QKV (bias by col segment, elu+1 on cols<1536, bf16 out)
//      1 = bias + f32 resid, f32 out
//      2 = bias + relu, bf16 out
template <int EPI>
__global__ __launch_bounds__(256) void gemm_mfma(
        const bf16* __restrict__ A, const bf16* __restrict__ Bt,
        const float* __restrict__ bias_q, const float* __restrict__ bias_k,
        const float* __restrict__ bias_v, const float* __restrict__ resid,
        float* __restrict__ outF, bf16* __restrict__ outB,
        int M, int N, int K) {
    __shared__ __attribute__((aligned(16))) bf16 As0[64][40];
    __shared__ __attribute__((aligned(16))) bf16 As1[64][40];
    __shared__ __attribute__((aligned(16))) bf16 Bs0[64][40];
    __shared__ __attribute__((aligned(16))) bf16 Bs1[64][40];
    int tid = threadIdx.x;
    int m0 = blockIdx.y * 64, n0 = blockIdx.x * 64;
    int w = tid >> 6;
    int l = tid & 63;
    int lm = l & 15, lq = l >> 4;
    int sr = tid >> 2;          // staging row 0..63
    int sk = (tid & 3) * 8;     // staging k offset within 32-chunk
    const bf16* Arow = &A[(size_t)(m0 + sr) * K];
    const bf16* Brow = &Bt[(size_t)(n0 + sr) * K];
    f32x4 acc[4] = {};
    // prefetch chunk 0
    uint4 a0 = *(const uint4*)&Arow[sk];
    uint4 a1 = *(const uint4*)&Arow[32 + sk];
    uint4 b0 = *(const uint4*)&Brow[sk];
    uint4 b1 = *(const uint4*)&Brow[32 + sk];
    for (int k0 = 0; k0 < K; k0 += 64) {
        __syncthreads();
        *(uint4*)&As0[sr][sk] = a0;
        *(uint4*)&As1[sr][sk] = a1;
        *(uint4*)&Bs0[sr][sk] = b0;
        *(uint4*)&Bs1[sr][sk] = b1;
        __syncthreads();
        int k2 = k0 + 64; if (k2 >= K) k2 = 0;      // tail: harmless re-read
        a0 = *(const uint4*)&Arow[k2 + sk];
        a1 = *(const uint4*)&Arow[k2 + 32 + sk];
        b0 = *(const uint4*)&Brow[k2 + sk];
        b1 = *(const uint4*)&Brow[k2 + 32 + sk];
        bf16x8 af0 = *(bf16x8*)&As0[w * 16 + lm][lq * 8];
        bf16x8 af1 = *(bf16x8*)&As1[w * 16 + lm][lq * 8];
#pragma unroll
        for (int nb = 0; nb < 4; nb++) {
            bf16x8 bf0 = *(bf16x8*)&Bs0[nb * 16 + lm][lq * 8];
            acc[nb] = __builtin_amdgcn_mfma_f32_16x16x32_bf16(af0, bf0, acc[nb], 0, 0, 0);
        }
#pragma unroll
        for (int nb = 0; nb < 4; nb++) {
            bf16x8 bf1 = *(bf16x8*)&Bs1[nb * 16 + lm][lq * 8];
            acc[nb] = __builtin_amdgcn_mfma_f32_16x16x32_bf16(af1, bf1, acc[nb], 0, 0, 0);
        }
    }
    // C layout: row = m0 + w*16 + lq*4 + r, col = n0 + nb*16 + lm
#pragma unroll
    for (int nb = 0; nb < 4; nb++) {
        int col = n0 + nb * 16 + lm;
        float b;
        bool do_elu = false;
        if (EPI == 0) {
            if (col < 768)       { b = bias_q[col];        do_elu = true; }
            else if (col < 1536) { b = bias_k[col - 768];  do_elu = true; }
            else                 { b = bias_v[col - 1536]; }
        } else {
            b = bias_q[col];
        }
#pragma unroll
        for (int r = 0; r < 4; r++) {
            int row = m0 + w * 16 + lq * 4 + r;
            float v = acc[nb][r] + b;
            if (EPI == 0) {
                if (do_elu) v = (v > 0.0f) ? (v + 1.0f) : expf(v);
                outB[(size_t)row * N + col] = (bf16)v;
            } else if (EPI == 1) {
                v += resid[(size_t)row * N + col];
                outF[(size_t)row * N + col] = v;
            } else {
                v = fmaxf(v, 0.0f);
                outB[(size_t)row * N + col] = (bf16)v;
            }
        }
    }
}

// ---------------- row LayerNorm over 768: one wave per row, no barriers ------
// grid: 160 blocks x 256 threads (4 waves = 4 rows per block).
__global__ __launch_bounds__(256) void ln_k(
        const float* __restrict__ in, float* __restrict__ outF,
        bf16* __restrict__ outB,
        const float* __restrict__ g, const float* __restrict__ b) {
    int wave = threadIdx.x >> 6, lane = threadIdx.x & 63;
    int row = blockIdx.x * 4 + wave;
    const float* xr = in + (size_t)row * DMODEL;
    float4 v[3];
    float s = 0.0f;
#pragma unroll
    for (int j = 0; j < 3; j++) {
        v[j] = *(const float4*)&xr[lane * 4 + 256 * j];
        s += v[j].x + v[j].y + v[j].z + v[j].w;
    }
#pragma unroll
    for (int mk = 1; mk < 64; mk <<= 1) s += __shfl_xor(s, mk, 64);
    float m = s * (1.0f / 768.0f);
    float sq = 0.0f;
#pragma unroll
    for (int j = 0; j < 3; j++) {
        v[j].x -= m; v[j].y -= m; v[j].z -= m; v[j].w -= m;
        sq += v[j].x * v[j].x + v[j].y * v[j].y + v[j].z * v[j].z + v[j].w * v[j].w;
    }
#pragma unroll
    for (int mk = 1; mk < 64; mk <<= 1) sq += __shfl_xor(sq, mk, 64);
    float r = rsqrtf(sq * (1.0f / 768.0f) + 1e-5f);
    float* orow = outF + (size_t)row * DMODEL;
    bf16* brow = outB + (size_t)row * DMODEL;
#pragma unroll
    for (int j = 0; j < 3; j++) {
        int c = lane * 4 + 256 * j;
        float4 gg = *(const float4*)&g[c];
        float4 bb = *(const float4*)&b[c];
        float o0 = v[j].x * r * gg.x + bb.x;
        float o1 = v[j].y * r * gg.y + bb.y;
        float o2 = v[j].z * r * gg.z + bb.z;
        float o3 = v[j].w * r * gg.w + bb.w;
        *(float4*)&orow[c] = make_float4(o0, o1, o2, o3);
        bf16 tmp4[4] = {(bf16)o0, (bf16)o1, (bf16)o2, (bf16)o3};
        *(uint2*)&brow[c] = *(uint2*)tmp4;
    }
}

// ---------------- causal linear attention as two MFMA matmuls (R5) -----------
__global__ __launch_bounds__(320) void attn_k(
        const bf16* __restrict__ qkvB, bf16* __restrict__ att) {
    __shared__ __attribute__((aligned(16))) char smem[64000];
    bf16* Qs = (bf16*)smem;            // [80][200]
    bf16* Ks = (bf16*)(smem + 32000);  // [80][200]
    bf16* Aij = (bf16*)smem;           // [80][104]  (overlays Qs after phase 1)
    bf16* VT = (bf16*)(smem + 16640);  // [192][104] (overlays Ks)

    int b = blockIdx.x >> 2, h = blockIdx.x & 3;
    int tid = threadIdx.x;
    int w = tid >> 6, l = tid & 63;
    int lm = l & 15, lq = l >> 4;

    uint4 vreg[6];
#pragma unroll
    for (int u = 0; u < 6; u++) {
        int c = tid + 320 * u;
        int t = c / 24, cc = c % 24;
        int d0 = cc * 8;
        size_t g = (size_t)(t * 8 + b) * NQKV + h * DH + d0;
        uint4 qv = *(const uint4*)&qkvB[g];
        uint4 kv = *(const uint4*)&qkvB[g + 768];
        vreg[u]  = *(const uint4*)&qkvB[g + 1536];
        *(uint4*)&Qs[t * 200 + d0] = qv;
        *(uint4*)&Ks[t * 200 + d0] = kv;
    }
    __syncthreads();

    f32x4 acc[5] = {};
#pragma unroll
    for (int k0 = 0; k0 < 192; k0 += 32) {
        bf16x8 af = *(bf16x8*)&Qs[(w * 16 + lm) * 200 + lq * 8 + k0];
#pragma unroll
        for (int nb = 0; nb < 5; nb++) {
            bf16x8 bfr = *(bf16x8*)&Ks[(nb * 16 + lm) * 200 + lq * 8 + k0];
            acc[nb] = __builtin_amdgcn_mfma_f32_16x16x32_bf16(af, bfr, acc[nb], 0, 0, 0);
        }
    }
    float mval[5][4];
    float rs[4] = {0.f, 0.f, 0.f, 0.f};
#pragma unroll
    for (int nb = 0; nb < 5; nb++)
#pragma unroll
        for (int r = 0; r < 4; r++) {
            int t = w * 16 + lq * 4 + r, tau = nb * 16 + lm;
            float v = (tau <= t) ? acc[nb][r] : 0.0f;
            mval[nb][r] = v;
            rs[r] += v;
        }
#pragma unroll
    for (int mk = 1; mk < 16; mk <<= 1)
#pragma unroll
        for (int r = 0; r < 4; r++) rs[r] += __shfl_xor(rs[r], mk, 64);
    float inv[4];
#pragma unroll
    for (int r = 0; r < 4; r++) inv[r] = 1.0f / (rs[r] + 1e-6f);

    __syncthreads();

#pragma unroll
    for (int nb = 0; nb < 5; nb++)
#pragma unroll
        for (int r = 0; r < 4; r++)
            Aij[(w * 16 + lq * 4 + r) * 104 + nb * 16 + lm] = (bf16)mval[nb][r];
    *(uint2*)&Aij[(tid >> 2) * 104 + 80 + (tid & 3) * 4] = make_uint2(0u, 0u);
#pragma unroll
    for (int u = 0; u < 6; u++) {
        int c = tid + 320 * u;
        int t = c / 24, cc = c % 24;
        int d0 = cc * 8;
        bf16 tmp8[8];
        *(uint4*)tmp8 = vreg[u];
#pragma unroll
        for (int j = 0; j < 8; j++) VT[(d0 + j) * 104 + t] = tmp8[j];
    }
    if (tid < 192) {
        *(uint4*)&VT[tid * 104 + 80] = make_uint4(0u, 0u, 0u, 0u);
        *(uint4*)&VT[tid * 104 + 88] = make_uint4(0u, 0u, 0u, 0u);
    }
    __syncthreads();

#pragma unroll 1
    for (int nc = 0; nc < 12; nc++) {
        f32x4 a2 = {};
#pragma unroll
        for (int k0 = 0; k0 < 96; k0 += 32) {
            bf16x8 af = *(bf16x8*)&Aij[(w * 16 + lm) * 104 + lq * 8 + k0];
            bf16x8 bfr = *(bf16x8*)&VT[(nc * 16 + lm) * 104 + lq * 8 + k0];
            a2 = __builtin_amdgcn_mfma_f32_16x16x32_bf16(af, bfr, a2, 0, 0, 0);
        }
#pragma unroll
        for (int r = 0; r < 4; r++) {
            int t = w * 16 + lq * 4 + r;
            att[(size_t)(t * 8 + b) * DMODEL + h * DH + nc * 16 + lm] =
                (bf16)(a2[r] * inv[r]);
        }
    }
}

// ---------------- final LN + output gather ----------------
__global__ __launch_bounds__(256) void final_k(
        const float* __restrict__ h, const int* __restrict__ act_ts,
        const float* __restrict__ g, const float* __restrict__ bb,
        float* __restrict__ out) {
    __shared__ float sm4[4];
    int ba = blockIdx.x;
    int b = ba / NA;
    int ts = act_ts[ba];
    int t = ts - 1; if (t < 0) t = 0;
    const float* xr = h + (size_t)(t * 8 + b) * DMODEL;
    int c = threadIdx.x;
    float x0 = xr[c], x1 = xr[c + 256], x2 = xr[c + 512];
    float m = block_reduce_sum256(x0 + x1 + x2, sm4) * (1.0f / 768.0f);
    float d0 = x0 - m, d1 = x1 - m, d2 = x2 - m;
    float v = block_reduce_sum256(d0 * d0 + d1 * d1 + d2 * d2, sm4) * (1.0f / 768.0f);
    float r = rsqrtf(v + 1e-5f);
    out[ba * 256 + c]            = d0 * r * g[c] + bb[c];                 // mu
    out[48 * 256 + ba * 256 + c] = d1 * r * g[c + 256] + bb[c + 256];     // logvar
}

extern "C" void kernel_launch(void* const* d_in, const int* in_sizes, int n_in,
                              void* d_out, int out_size, void* d_ws, size_t ws_size,
                              hipStream_t stream) {
    const float* x       = (const float*)d_in[0];
    const int*   y       = (const int*)d_in[1];
    const int*   ind_map = (const int*)d_in[2];
    const int*   act_ts  = (const int*)d_in[3];
    const float* skel_W  = (const float*)d_in[4];
    const float* skel_b  = (const float*)d_in[5];
    const float* muQ     = (const float*)d_in[6];
    const float* sigQ    = (const float*)d_in[7];
    const float* Wq = (const float*)d_in[8];   const float* bq = (const float*)d_in[9];
    const float* Wk = (const float*)d_in[10];  const float* bk = (const float*)d_in[11];
    const float* Wv = (const float*)d_in[12];  const float* bv = (const float*)d_in[13];
    const float* Wo = (const float*)d_in[14];  const float* bo = (const float*)d_in[15];
    const float* W1 = (const float*)d_in[16];  const float* b1 = (const float*)d_in[17];
    const float* W2 = (const float*)d_in[18];  const float* b2 = (const float*)d_in[19];
    const float* ln1_g = (const float*)d_in[20]; const float* ln1_b = (const float*)d_in[21];
    const float* ln2_g = (const float*)d_in[22]; const float* ln2_b = (const float*)d_in[23];
    const float* lnf_g = (const float*)d_in[24]; const float* lnf_b = (const float*)d_in[25];
    float* out = (float*)d_out;

    // ---- workspace layout (all 16B aligned) ----
    char* p = (char*)d_ws;
    const size_t R  = (size_t)NROWS * DMODEL;      // 491520
    float* h    = (float*)p; p += R * 4;
    float* h1   = (float*)p; p += R * 4;
    float* tmp  = (float*)p; p += R * 4;
    bf16* qkvB  = (bf16*)p;  p += (size_t)NROWS * NQKV * 2;
    bf16* hB    = (bf16*)p;  p += R * 2;
    bf16* h1B   = (bf16*)p;  p += R * 2;
    bf16* attB  = (bf16*)p;  p += R * 2;
    bf16* ffn1B = (bf16*)p;  p += (size_t)NROWS * FFD * 2;
    bf16* qkvT  = (bf16*)p;  p += (size_t)4 * NQKV * DMODEL * 2;
    bf16* woT   = (bf16*)p;  p += (size_t)4 * DMODEL * DMODEL * 2;
    bf16* w1T   = (bf16*)p;  p += (size_t)4 * FFD * DMODEL * 2;
    bf16* w2T   = (bf16*)p;  p += (size_t)4 * DMODEL * FFD * 2;

    // weight prep + embedding fused into one dispatch (independent halves)
    prep_k<<<512 + NROWS, 256, 0, stream>>>(
            x, y, ind_map, skel_W, skel_b, muQ, sigQ, h, hB,
            Wq, Wk, Wv, Wo, W1, W2, qkvT, woT, w1T, w2T);

    dim3 gQKV(NQKV / 64, 10);
    dim3 g768(12, 10);
    dim3 g1024(16, 10);
    for (int l = 0; l < 4; l++) {
        const bf16* qkvTl = qkvT + (size_t)l * NQKV * DMODEL;
        const bf16* woTl  = woT  + (size_t)l * DMODEL * DMODEL;
        const bf16* w1Tl  = w1T  + (size_t)l * FFD * DMODEL;
        const bf16* w2Tl  = w2T  + (size_t)l * DMODEL * FFD;
        // QKV fused: [640,768] @ [768,2304] -> qkvB bf16 (elu+1 on Q,K)
        gemm_mfma<0><<<gQKV, 256, 0, stream>>>(hB, qkvTl,
                bq + l * DMODEL, bk + l * DMODEL, bv + l * DMODEL,
                nullptr, nullptr, qkvB, NROWS, NQKV, DMODEL);
        attn_k<<<32, 320, 0, stream>>>(qkvB, attB);
        // att @ Wo + bo + h -> tmp
        gemm_mfma<1><<<g768, 256, 0, stream>>>(attB, woTl,
                bo + l * DMODEL, nullptr, nullptr, h, tmp, nullptr,
                NROWS, DMODEL, DMODEL);
        ln_k<<<NROWS / 4, 256, 0, stream>>>(tmp, h1, h1B, ln1_g + l * DMODEL, ln1_b + l * DMODEL);
        // relu(h1 @ W1 + b1) -> ffn1 (bf16)
        gemm_mfma<2><<<g1024, 256, 0, stream>>>(h1B, w1Tl,
                b1 + l * FFD, nullptr, nullptr, nullptr, nullptr, ffn1B,
                NROWS, FFD, DMODEL);
        // ffn1 @ W2 + b2 + h1 -> tmp
        gemm_mfma<1><<<g768, 256, 0, stream>>>(ffn1B, w2Tl,
                b2 + l * DMODEL, nullptr, nullptr, h1, tmp, nullptr,
                NROWS, DMODEL, FFD);
        ln_k<<<NROWS / 4, 256, 0, stream>>>(tmp, h, hB, ln2_g + l * DMODEL, ln2_b + l * DMODEL);
    }

    final_k<<<48, 256, 0, stream>>>(h, act_ts, lnf_g, lnf_b, out);
}